// Round 1
// baseline (191.020 us; speedup 1.0000x reference)
//
#include <hip/hip_runtime.h>
#include <hip/hip_bf16.h>
#include <stdint.h>

#define N_B 2
#define T_S 2048
#define D_M 1024
#define H_N 16
#define D_H 64

typedef __bf16 bf16_t;
typedef __bf16 bf16x8 __attribute__((ext_vector_type(8)));
typedef float f32x4 __attribute__((ext_vector_type(4)));

__device__ __forceinline__ void async_ld16(const void* g, void* lds_uniform_base) {
  __builtin_amdgcn_global_load_lds(
      (const __attribute__((address_space(1))) uint32_t*)(uintptr_t)g,
      (__attribute__((address_space(3))) uint32_t*)(uintptr_t)lds_uniform_base,
      16, 0, 0);
}

// ---------------- fp32 -> bf16 convert (vectorized) ----------------
__global__ __launch_bounds__(256) void cvt_kernel(const float* __restrict__ in,
                                                  bf16_t* __restrict__ out, int n4) {
  int i = blockIdx.x * blockDim.x + threadIdx.x;
  if (i < n4) {
    float4 v = ((const float4*)in)[i];
    union { bf16_t b[4]; uint64_t u; } o;
    o.b[0] = (bf16_t)v.x; o.b[1] = (bf16_t)v.y;
    o.b[2] = (bf16_t)v.z; o.b[3] = (bf16_t)v.w;
    *(uint64_t*)(out + (size_t)i * 4) = o.u;
  }
}

// ---------------- fp32 -> bf16 convert + transpose (for W) ----------------
// in: [R][C] f32 row-major, out: [C][R] bf16 row-major
__global__ __launch_bounds__(256) void transpose_cvt_kernel(const float* __restrict__ in,
                                                            bf16_t* __restrict__ out,
                                                            int R, int C) {
  __shared__ float tile[32][33];
  int bx = blockIdx.x * 32;  // col block of in
  int by = blockIdx.y * 32;  // row block of in
  int tx = threadIdx.x, ty = threadIdx.y;  // (32,8)
#pragma unroll
  for (int i = 0; i < 32; i += 8)
    tile[ty + i][tx] = in[(size_t)(by + ty + i) * C + bx + tx];
  __syncthreads();
#pragma unroll
  for (int i = 0; i < 32; i += 8)
    out[(size_t)(bx + ty + i) * R + by + tx] = (bf16_t)tile[tx][ty + i];
}

// ---------------- bf16 GEMM, C = A @ Bt^T  (m97 structure) ----------------
// A: [M][1024], Bt: [N][1024] (i.e. B transposed), both bf16 row-major.
// MODE 0: scatter epilogue into Q/K/Vt head layouts.  MODE 1: +bias, fp32 out.
template <int MODE>
__global__ __launch_bounds__(256) void gemm_bt_kernel(
    const bf16_t* __restrict__ A, const bf16_t* __restrict__ Bt,
    bf16_t* __restrict__ Qo, bf16_t* __restrict__ Ko, bf16_t* __restrict__ Vto,
    const float* __restrict__ bias, float* __restrict__ Co) {
  __shared__ bf16_t As[128 * 32];
  __shared__ bf16_t Bs[128 * 32];
  const int tid = threadIdx.x;
  const int lane = tid & 63;
  const int wid = tid >> 6;
  const int wr = wid >> 1, wc = wid & 1;
  const int g = lane >> 4, lr = lane & 15;
  const int brow = blockIdx.y * 128;
  const int bcol = blockIdx.x * 128;

  f32x4 acc[4][4] = {};

  for (int k0 = 0; k0 < 1024; k0 += 32) {
#pragma unroll
    for (int q = 0; q < 2; ++q) {
      int idx = wid * 128 + q * 64 + lane;
      int row = idx >> 2, part = (idx & 3) * 8;
      async_ld16(A + (size_t)(brow + row) * 1024 + k0 + part,
                 &As[(wid * 128 + q * 64) * 8]);
      async_ld16(Bt + (size_t)(bcol + row) * 1024 + k0 + part,
                 &Bs[(wid * 128 + q * 64) * 8]);
    }
    __syncthreads();
    bf16x8 af[4], bfr[4];
#pragma unroll
    for (int i = 0; i < 4; ++i) {
      af[i]  = *(const bf16x8*)&As[(wr * 64 + i * 16 + lr) * 32 + g * 8];
      bfr[i] = *(const bf16x8*)&Bs[(wc * 64 + i * 16 + lr) * 32 + g * 8];
    }
#pragma unroll
    for (int i = 0; i < 4; ++i)
#pragma unroll
      for (int j = 0; j < 4; ++j)
        acc[i][j] = __builtin_amdgcn_mfma_f32_16x16x32_bf16(af[i], bfr[j], acc[i][j], 0, 0, 0);
    __syncthreads();
  }

#pragma unroll
  for (int i = 0; i < 4; ++i) {
    int row0 = brow + wr * 64 + i * 16 + g * 4;
#pragma unroll
    for (int j = 0; j < 4; ++j) {
      int col = bcol + wc * 64 + j * 16 + lr;
#pragma unroll
      for (int r = 0; r < 4; ++r) {
        int row = row0 + r;
        float v = acc[i][j][r];
        if (MODE == 0) {
          int n = row >> 11, t = row & (T_S - 1);
          int which = col >> 10, d = col & (D_M - 1);
          int h = d >> 6, dh = d & 63;
          if (which == 0)
            Qo[((size_t)(n * H_N + h) * T_S + t) * D_H + dh] = (bf16_t)v;
          else if (which == 1)
            Ko[((size_t)(n * H_N + h) * T_S + t) * D_H + dh] = (bf16_t)v;
          else
            Vto[((size_t)(n * H_N + h) * D_H + dh) * T_S + t] = (bf16_t)v;
        } else {
          Co[(size_t)row * D_M + col] = v + bias[col];
        }
      }
    }
  }
}

// ---------------- causal flash attention ----------------
// Q,K: [n,h,t,dh] bf16 ; Vt: [n,h,dh,t] bf16 ; O: [n,t,d] bf16
__global__ __launch_bounds__(256) void attn_kernel(const bf16_t* __restrict__ Q,
                                                   const bf16_t* __restrict__ K,
                                                   const bf16_t* __restrict__ Vt,
                                                   bf16_t* __restrict__ O) {
  __shared__ bf16_t Ks[64 * 64];
  __shared__ bf16_t Vs[64 * 64];
  __shared__ bf16_t Ps[4][16 * 64];

  const int tid = threadIdx.x;
  const int lane = tid & 63;
  const int w = tid >> 6;
  const int g = lane >> 4, lr = lane & 15;
  const int qc = gridDim.x - 1 - blockIdx.x;  // heavy blocks dispatched first
  const int qb = qc * 64;
  const int nh = blockIdx.y;
  const bf16_t* Qg = Q + (size_t)nh * T_S * D_H;
  const bf16_t* Kg = K + (size_t)nh * T_S * D_H;
  const bf16_t* Vg = Vt + (size_t)nh * D_H * T_S;

  const int q0 = qb + w * 16;

  bf16x8 qf[2];
  qf[0] = *(const bf16x8*)(Qg + (size_t)(q0 + lr) * D_H + g * 8);
  qf[1] = *(const bf16x8*)(Qg + (size_t)(q0 + lr) * D_H + 32 + g * 8);

  f32x4 o_acc[4] = {};
  float m_run[4] = {-INFINITY, -INFINITY, -INFINITY, -INFINITY};
  float l_run[4] = {0.f, 0.f, 0.f, 0.f};

  const int ntiles = qc + 1;
  for (int kt = 0; kt < ntiles; ++kt) {
    // stage K tile [64 keys][64 d] and V tile [64 d][64 keys], XOR-swizzled
    for (int c = tid; c < 512; c += 256) {
      int row = c >> 3, colb = (c & 7) * 16;
      uint4 kv = *(const uint4*)((const char*)(Kg + (size_t)(kt * 64 + row) * D_H) + colb);
      uint4 vv = *(const uint4*)((const char*)(Vg + (size_t)row * T_S + kt * 64) + colb);
      int sw = (row & 7) << 4;
      *(uint4*)((char*)Ks + ((row * 128 + colb) ^ sw)) = kv;
      *(uint4*)((char*)Vs + ((row * 128 + colb) ^ sw)) = vv;
    }
    __syncthreads();

    // S = Q K^T  (per wave: 16 q x 64 k)
    f32x4 s[4];
#pragma unroll
    for (int j = 0; j < 4; ++j) {
      f32x4 a = {};
#pragma unroll
      for (int ks = 0; ks < 2; ++ks) {
        int row = j * 16 + lr;
        int cb = (ks * 32 + g * 8) * 2;
        bf16x8 kf = *(const bf16x8*)((char*)Ks + ((row * 128 + cb) ^ ((row & 7) << 4)));
        a = __builtin_amdgcn_mfma_f32_16x16x32_bf16(qf[ks], kf, a, 0, 0, 0);
      }
      s[j] = a;
    }

    const bool last = (kt == ntiles - 1);
#pragma unroll
    for (int j = 0; j < 4; ++j)
#pragma unroll
      for (int r = 0; r < 4; ++r) {
        float v = s[j][r] * 0.125f;
        if (last) {
          int kabs = kt * 64 + j * 16 + lr;
          int qabs = q0 + g * 4 + r;
          if (kabs > qabs) v = -1.0e30f;
        }
        s[j][r] = v;
      }

    // online softmax (row spread over the 16 lanes of each g-group)
#pragma unroll
    for (int r = 0; r < 4; ++r) {
      float m = fmaxf(fmaxf(s[0][r], s[1][r]), fmaxf(s[2][r], s[3][r]));
#pragma unroll
      for (int off = 1; off < 16; off <<= 1) m = fmaxf(m, __shfl_xor(m, off, 64));
      float mn = fmaxf(m_run[r], m);
      float alpha = __expf(m_run[r] - mn);
      float sum = 0.f;
#pragma unroll
      for (int j = 0; j < 4; ++j) {
        float p = __expf(s[j][r] - mn);
        s[j][r] = p;
        sum += p;
      }
#pragma unroll
      for (int off = 1; off < 16; off <<= 1) sum += __shfl_xor(sum, off, 64);
      l_run[r] = l_run[r] * alpha + sum;
      m_run[r] = mn;
#pragma unroll
      for (int d = 0; d < 4; ++d) o_acc[d][r] *= alpha;
    }

    // P -> wave-private LDS (bf16, swizzled), no barrier needed
#pragma unroll
    for (int j = 0; j < 4; ++j)
#pragma unroll
      for (int r = 0; r < 4; ++r) {
        int row = g * 4 + r;
        int cb = (j * 16 + lr) * 2;
        *(bf16_t*)((char*)Ps[w] + ((row * 128 + cb) ^ ((row & 7) << 4))) = (bf16_t)s[j][r];
      }

    // O += P V
    bf16x8 pf[2];
#pragma unroll
    for (int ks = 0; ks < 2; ++ks) {
      int cb = (ks * 32 + g * 8) * 2;
      pf[ks] = *(const bf16x8*)((char*)Ps[w] + ((lr * 128 + cb) ^ ((lr & 7) << 4)));
    }
#pragma unroll
    for (int d = 0; d < 4; ++d) {
#pragma unroll
      for (int ks = 0; ks < 2; ++ks) {
        int row = d * 16 + lr;
        int cb = (ks * 32 + g * 8) * 2;
        bf16x8 vf = *(const bf16x8*)((char*)Vs + ((row * 128 + cb) ^ ((row & 7) << 4)));
        o_acc[d] = __builtin_amdgcn_mfma_f32_16x16x32_bf16(pf[ks], vf, o_acc[d], 0, 0, 0);
      }
    }
    __syncthreads();
  }

  const int n = nh >> 4, h = nh & 15;
#pragma unroll
  for (int r = 0; r < 4; ++r) {
    int t = q0 + g * 4 + r;
    float inv = 1.f / l_run[r];
#pragma unroll
    for (int d = 0; d < 4; ++d)
      O[(size_t)(n * T_S + t) * D_M + h * D_H + d * 16 + lr] = (bf16_t)(o_acc[d][r] * inv);
  }
}

extern "C" void kernel_launch(void* const* d_in, const int* in_sizes, int n_in,
                              void* d_out, int out_size, void* d_ws, size_t ws_size,
                              hipStream_t stream) {
  const float* x  = (const float*)d_in[0];
  const float* W  = (const float*)d_in[1];
  const float* pw = (const float*)d_in[2];
  const float* pb = (const float*)d_in[3];
  float* out = (float*)d_out;

  char* ws = (char*)d_ws;
  bf16_t* x_bf = (bf16_t*)(ws);                      //  8 MB: [4096][1024]
  bf16_t* Wt   = (bf16_t*)(ws + (8ull  << 20));      //  6 MB: [3072][1024]
  bf16_t* pwb  = (bf16_t*)(ws + (14ull << 20));      //  2 MB: [1024][1024]
  bf16_t* Qh   = (bf16_t*)(ws + (16ull << 20));      //  8 MB: [2,16,2048,64]
  bf16_t* Kh   = (bf16_t*)(ws + (24ull << 20));      //  8 MB
  bf16_t* Vth  = (bf16_t*)(ws + (32ull << 20));      //  8 MB: [2,16,64,2048]
  bf16_t* Oa   = (bf16_t*)(ws + (40ull << 20));      //  8 MB: [4096][1024]

  cvt_kernel<<<4096, 256, 0, stream>>>(x, x_bf, (4096 * 1024) / 4);
  transpose_cvt_kernel<<<dim3(96, 32), dim3(32, 8), 0, stream>>>(W, Wt, 1024, 3072);
  cvt_kernel<<<1024, 256, 0, stream>>>(pw, pwb, (1024 * 1024) / 4);

  gemm_bt_kernel<0><<<dim3(24, 32), 256, 0, stream>>>(x_bf, Wt, Qh, Kh, Vth, nullptr, nullptr);

  attn_kernel<<<dim3(32, 32), 256, 0, stream>>>(Qh, Kh, Vth, Oa);

  gemm_bt_kernel<1><<<dim3(8, 32), 256, 0, stream>>>(Oa, pwb, nullptr, nullptr, nullptr, pb, out);
}